// Round 13
// baseline (150.392 us; speedup 1.0000x reference)
//
#include <hip/hip_runtime.h>
#include <hip/hip_bf16.h>

typedef __attribute__((ext_vector_type(4))) float f32x4;
typedef __attribute__((ext_vector_type(8))) short bf16x8;

#define MFMA(a, b, c) __builtin_amdgcn_mfma_f32_16x16x32_bf16(a, b, c, 0, 0, 0)

__device__ __forceinline__ short f2bf(float f) {
    union { float f; unsigned u; } v; v.f = f;
    unsigned r = v.u + 0x7fffu + ((v.u >> 16) & 1u);
    return (short)(r >> 16);
}

__device__ __forceinline__ short f2bf_h(float f) {
    __hip_bfloat16 h = __float2bfloat16(f);
    return *reinterpret_cast<const short*>(&h);
}

__device__ __forceinline__ bf16x8 cvt8h(f32x4 a, f32x4 b) {
    bf16x8 r;
    #pragma unroll
    for (int i = 0; i < 4; ++i) {
        r[i]     = f2bf_h(a[i]);
        r[4 + i] = f2bf_h(b[i]);
    }
    return r;
}

__device__ __forceinline__ void gll16(const void* g, const void* l) {
    __builtin_amdgcn_global_load_lds(
        (const __attribute__((address_space(1))) void*)g,
        (__attribute__((address_space(3))) void*)l, 16, 0, 0);
}

// ws layout:
//   W_frag [32 chunks][20 tiles][64 lanes] bf16x8 @ short 0   (327680 shorts)
//     tile = j*4 + wid (j=seg 0..4: q,k1,v1,k2,v2); lane=(lkg<<4)|lrow holds
//     W[j*64 + wid*16 + lrow][c*32 + lkg*8 .. +8]  -> wave load = 1KB dense
//   weff  [1024][64] bf16 @ short 327680
//   b_all [320]      f32  @ byte 786432
#define WS_WEFF   327680
#define WS_BALL_B 786432

__global__ __launch_bounds__(256) void prep_kernel(
        const float* __restrict__ lq_w, const float* __restrict__ lk1_w,
        const float* __restrict__ lk2_w, const float* __restrict__ lv1_w,
        const float* __restrict__ lv2_w, const float* __restrict__ lh_w,
        const float* __restrict__ lq_b, const float* __restrict__ lk1_b,
        const float* __restrict__ lk2_b, const float* __restrict__ lv1_b,
        const float* __restrict__ lv2_b,
        short* __restrict__ W_frag, short* __restrict__ weff,
        float* __restrict__ b_all) {
    int t = blockIdx.x * 256 + threadIdx.x;
    if (t < 327680) {                       // W_frag (fragment-order layout)
        const int e    = t & 7;             // element within bf16x8
        const int u16  = t >> 3;            // 16B cell index
        const int lane = u16 & 63;
        const int tl   = u16 >> 6;          // 0..639 = c*20 + tt
        const int c    = tl / 20;
        const int tt   = tl - c * 20;
        const int j    = tt >> 2;           // segment
        const int wd   = tt & 3;            // wave
        const int lrow = lane & 15;
        const int lkg  = lane >> 4;
        const float* src = (j == 0) ? lq_w : (j == 1) ? lk1_w
                         : (j == 2) ? lv1_w : (j == 3) ? lk2_w : lv2_w;
        W_frag[t] = f2bf(src[(wd * 16 + lrow) * 1024 + c * 32 + lkg * 8 + e]);
    } else if (t < 393216) {                // weff
        int i = t - 327680;
        int jj = i >> 6, d = i & 63;
        float s = 0.f;
        #pragma unroll
        for (int h = 0; h < 16; ++h) s += lh_w[jj * 1024 + h * 64 + d];
        weff[i] = f2bf(s);
    } else if (t < 393536) {                // b_all
        int i = t - 393216;
        int seg = i >> 6, si = i & 63;
        const float* src = (seg == 0) ? lq_b : (seg == 1) ? lk1_b
                         : (seg == 2) ? lv1_b : (seg == 3) ? lk2_b : lv2_b;
        b_all[i] = src[si];
    }
}

// Fused: block = 32 rows, 4 waves, K=1024 in 32 bodies of 32.
// Ring-3 A (36KB LDS -> 4 blocks/CU, 1024 blocks = ONE batch, zero tail),
// R11's PROVEN body ordering: compute -> W(C+2) into just-consumed bank ->
// A(C+2) into slot (K+2)%3 (read at body C-1; finished) -> vmcnt(8)
// (drains exactly A(C+1)3+W(C+1)5) -> barrier. All prefetch issued AFTER
// the MFMAs (every passing kernel used this ordering; R10/R12's body-top
// issue failed). Slim epilogue (29.8KB) fits the 36KB budget.
__global__ __launch_bounds__(256, 3) void fused_kernel(
        const float* __restrict__ Q, const float* __restrict__ K,
        const float* __restrict__ V, const short* __restrict__ W_frag,
        const float* __restrict__ b_all, const short* __restrict__ weff,
        const float* __restrict__ lh_b, float* __restrict__ out) {
    __shared__ __align__(16) char lds[36864];   // 3 x 12KB A ring; epi reuse
    const int tid  = threadIdx.x;
    const int wid  = tid >> 6;
    const int lane = tid & 63;
    const int lrow = lane & 15;
    const int lkg  = lane >> 4;
    const int RB   = blockIdx.x * 32;

    // A staging: 12 gll/body (1KB = 8 rows x 128B), 3/wave. Source XOR-swizzle
    // within the 8-cell row chunk; LDS dest linear [input][row][128B].
    const float* asrc[3];
    int adst[3];
    #pragma unroll
    for (int u = 0; u < 3; ++u) {
        const int i   = wid * 3 + u;        // 0..11
        const int inp = i >> 2;             // 0=Q 1=K 2=V
        const int rg  = i & 3;              // 8-row group
        const int row = rg * 8 + (lane >> 3);
        const int gc  = (lane & 7) ^ (row & 7);
        const float* base = (inp == 0) ? Q : (inp == 1) ? K : V;
        asrc[u] = base + (size_t)(RB + row) * 1024 + gc * 4;
        adst[u] = inp * 4096 + rg * 1024;
    }

    // W fragment pointers: tile (j*4+wid), this lane's 16B cell. Dense 1KB/wave.
    const short* wsrc[5];
    #pragma unroll
    for (int j = 0; j < 5; ++j)
        wsrc[j] = W_frag + (size_t)((j * 4 + wid) * 64 + lane) * 8;

    f32x4 acc[2][5];
    #pragma unroll
    for (int rt = 0; rt < 2; ++rt)
        #pragma unroll
        for (int j = 0; j < 5; ++j) acc[rt][j] = (f32x4){0.f, 0.f, 0.f, 0.f};

    bf16x8 wE[5], wO[5];                    // 2 W reg banks (even/odd bodies)
    const int r7 = lrow & 7;
    const int c0 = ((lkg * 2)     ^ r7) << 4;
    const int c1 = ((lkg * 2 + 1) ^ r7) << 4;

#define GLD4(dst, p) \
    asm volatile("global_load_dwordx4 %0, %1, off" : "=&v"(dst) : "v"(p) : "memory")

    // ---- prologue FIFO: A(0)3, W(0)5, A(1)3, W(1)5 = 16 ----
    #pragma unroll
    for (int u = 0; u < 3; ++u) gll16(asrc[u], lds + adst[u]);
    #pragma unroll
    for (int j = 0; j < 5; ++j) GLD4(wE[j], wsrc[j]);
    #pragma unroll
    for (int u = 0; u < 3; ++u) gll16(asrc[u] + 32, lds + 12288 + adst[u]);
    #pragma unroll
    for (int j = 0; j < 5; ++j) GLD4(wO[j], wsrc[j] + 10240);
    asm volatile("s_waitcnt vmcnt(8)" ::: "memory");   // drains A(0)3+W(0)5
    __builtin_amdgcn_sched_barrier(0);
    __builtin_amdgcn_s_barrier();
    __builtin_amdgcn_sched_barrier(0);

    // BODY(C, K, WB): K = literal, K == C mod 6 (K%3 == C%3, K&1 == C&1).
    // Entry in-flight: [A(C+1)3, W(C+1)5].
#define BODY(C, K, WB)                                                         \
    {                                                                          \
        /* compute: slot K%3 (A(C), drained end of C-1), bank WB (W(C)) */     \
        const char* Ab = lds + (K) % 3 * 12288;                                \
        bf16x8 fq[2], fk[2], fv[2];                                            \
        _Pragma("unroll")                                                      \
        for (int rt = 0; rt < 2; ++rt) {                                       \
            const int ro = (rt * 16 + lrow) * 128;                             \
            f32x4 q0 = *(const f32x4*)(Ab + ro + c0);                          \
            f32x4 q1 = *(const f32x4*)(Ab + ro + c1);                          \
            f32x4 k0 = *(const f32x4*)(Ab + 4096 + ro + c0);                   \
            f32x4 k1 = *(const f32x4*)(Ab + 4096 + ro + c1);                   \
            f32x4 v0 = *(const f32x4*)(Ab + 8192 + ro + c0);                   \
            f32x4 v1 = *(const f32x4*)(Ab + 8192 + ro + c1);                   \
            fq[rt] = cvt8h(q0, q1);                                            \
            fk[rt] = cvt8h(k0, k1);                                            \
            fv[rt] = cvt8h(v0, v1);                                            \
        }                                                                      \
        _Pragma("unroll")                                                      \
        for (int rt = 0; rt < 2; ++rt) {                                       \
            acc[rt][0] = MFMA(fq[rt], WB[0], acc[rt][0]);                      \
            acc[rt][1] = MFMA(fk[rt], WB[1], acc[rt][1]);                      \
            acc[rt][2] = MFMA(fk[rt], WB[2], acc[rt][2]);                      \
            acc[rt][3] = MFMA(fv[rt], WB[3], acc[rt][3]);                      \
            acc[rt][4] = MFMA(fv[rt], WB[4], acc[rt][4]);                      \
        }                                                                      \
        __builtin_amdgcn_sched_barrier(0);                                     \
        /* W(C+2) into WB (just consumed; write lands >=200cy later) */        \
        const int kw = ((C) + 2 <= 31) ? (C) + 2 : 31;                         \
        _Pragma("unroll")                                                      \
        for (int j = 0; j < 5; ++j) GLD4(WB[j], wsrc[j] + kw * 10240);         \
        /* A(C+2) into slot (K+2)%3 (read finished at body C-1) */             \
        const int ka = ((C) + 2 <= 31) ? (C) + 2 : 31;                         \
        char* Db = lds + ((K) + 2) % 3 * 12288;                                \
        _Pragma("unroll")                                                      \
        for (int u = 0; u < 3; ++u) gll16(asrc[u] + ka * 32, Db + adst[u]);    \
        __builtin_amdgcn_sched_barrier(0);                                     \
        asm volatile("s_waitcnt vmcnt(8)" ::: "memory");                       \
        __builtin_amdgcn_sched_barrier(0);                                     \
        __builtin_amdgcn_s_barrier();                                          \
        __builtin_amdgcn_sched_barrier(0);                                     \
    }

    #pragma unroll 1
    for (int g = 0; g < 5; ++g) {           // bodies 0..29 (base = 6g)
        const int base = g * 6;
        BODY(base + 0, 0, wE) BODY(base + 1, 1, wO) BODY(base + 2, 2, wE)
        BODY(base + 3, 3, wO) BODY(base + 4, 4, wE) BODY(base + 5, 5, wO)
    }
    BODY(30, 0, wE) BODY(31, 1, wO)         // 30 % 6 == 0 keeps K alignment
#undef BODY
#undef GLD4

    // drain tail junk (dead slots/banks), then reuse LDS
    asm volatile("s_waitcnt vmcnt(0)" ::: "memory");
    __builtin_amdgcn_sched_barrier(0);
    __syncthreads();

    // ---- slim gate epilogue (29.8KB): q/k1/k2 panels -> dots -> g12 -> head
    float* qa  = (float*)lds;               // [32][65] f32
    float* k1a = qa  + 32 * 65;
    float* k2a = k1a + 32 * 65;
    float* g12 = k2a + 32 * 65;             // [32][2]
    short* head_s = (short*)(g12 + 64);     // [32][72] bf16

    const int segc = wid * 16 + lrow;
    #pragma unroll
    for (int rt = 0; rt < 2; ++rt) {
        #pragma unroll
        for (int i = 0; i < 4; ++i) {
            const int row = rt * 16 + lkg * 4 + i;
            qa [row * 65 + segc] = acc[rt][0][i] + b_all[segc];
            k1a[row * 65 + segc] = acc[rt][1][i] + b_all[64 + segc];
            k2a[row * 65 + segc] = acc[rt][3][i] + b_all[192 + segc];
        }
    }
    __syncthreads();

    // gate: row r = tid>>3, part p = tid&7 (8 lanes/row, in-wave reduce)
    {
        const int r = tid >> 3;
        const int p = tid & 7;
        float p1 = 0.f, p2 = 0.f;
        #pragma unroll
        for (int jj = 0; jj < 8; ++jj) {
            const float qv = qa[r * 65 + p * 8 + jj];
            p1 += qv * k1a[r * 65 + p * 8 + jj];
            p2 += qv * k2a[r * 65 + p * 8 + jj];
        }
        p1 += __shfl_xor(p1, 1, 64); p1 += __shfl_xor(p1, 2, 64); p1 += __shfl_xor(p1, 4, 64);
        p2 += __shfl_xor(p2, 1, 64); p2 += __shfl_xor(p2, 2, 64); p2 += __shfl_xor(p2, 4, 64);
        if (p == 0) {
            const float mx = fmaxf(p1, p2);
            const float e1 = __expf(p1 - mx);
            const float e2 = __expf(p2 - mx);
            const float inv = 1.f / (e1 + e2);
            g12[r * 2]     = e1 * inv;
            g12[r * 2 + 1] = e2 * inv;
        }
    }
    __syncthreads();

    // head from in-register v1/v2 (+bias), gated by g12[row]
    {
        const float bv1 = b_all[128 + segc];
        const float bv2 = b_all[256 + segc];
        #pragma unroll
        for (int rt = 0; rt < 2; ++rt) {
            #pragma unroll
            for (int i = 0; i < 4; ++i) {
                const int row = rt * 16 + lkg * 4 + i;
                const float g1 = g12[row * 2];
                const float g2 = g12[row * 2 + 1];
                const float h = g1 * (acc[rt][2][i] + bv1)
                              + g2 * (acc[rt][4][i] + bv2);
                head_s[row * 72 + segc] = f2bf_h(h);
            }
        }
    }
    __syncthreads();

    // ---- phase 2: out[32 x 1024] = head @ W_eff^T + lh_b; wave = 256 cols ----
    bf16x8 ha[2][2];
    #pragma unroll
    for (int rt = 0; rt < 2; ++rt) {
        ha[rt][0] = *(const bf16x8*)(head_s + (rt * 16 + lrow) * 72 + lkg * 8);
        ha[rt][1] = *(const bf16x8*)(head_s + (rt * 16 + lrow) * 72 + 32 + lkg * 8);
    }
    const int cgbase = wid * 256;
    #pragma unroll 4
    for (int jt = 0; jt < 16; ++jt) {
        const int col = cgbase + jt * 16 + lrow;
        const float bb = lh_b[col];
        const short* wp = weff + col * 64 + lkg * 8;
        const bf16x8 w0 = *(const bf16x8*)(wp);
        const bf16x8 w1 = *(const bf16x8*)(wp + 32);
        #pragma unroll
        for (int rt = 0; rt < 2; ++rt) {
            f32x4 a = {bb, bb, bb, bb};
            a = MFMA(ha[rt][0], w0, a);
            a = MFMA(ha[rt][1], w1, a);
            #pragma unroll
            for (int i = 0; i < 4; ++i)
                out[(size_t)(RB + rt * 16 + lkg * 4 + i) * 1024 + col] = a[i];
        }
    }
}

extern "C" void kernel_launch(void* const* d_in, const int* in_sizes, int n_in,
                              void* d_out, int out_size, void* d_ws, size_t ws_size,
                              hipStream_t stream) {
    const float* Q     = (const float*)d_in[0];
    const float* K     = (const float*)d_in[1];
    const float* V     = (const float*)d_in[2];
    const float* lq_w  = (const float*)d_in[3];
    const float* lq_b  = (const float*)d_in[4];
    const float* lk1_w = (const float*)d_in[5];
    const float* lk1_b = (const float*)d_in[6];
    const float* lk2_w = (const float*)d_in[7];
    const float* lk2_b = (const float*)d_in[8];
    const float* lv1_w = (const float*)d_in[9];
    const float* lv1_b = (const float*)d_in[10];
    const float* lv2_w = (const float*)d_in[11];
    const float* lv2_b = (const float*)d_in[12];
    const float* lh_w  = (const float*)d_in[13];
    const float* lh_b  = (const float*)d_in[14];
    float* out = (float*)d_out;

    short* W_frag = (short*)d_ws;
    short* weff   = W_frag + WS_WEFF;
    float* b_all  = (float*)((char*)d_ws + WS_BALL_B);

    prep_kernel<<<1538, 256, 0, stream>>>(lq_w, lk1_w, lk2_w, lv1_w, lv2_w, lh_w,
                                          lq_b, lk1_b, lk2_b, lv1_b, lv2_b,
                                          W_frag, weff, b_all);
    fused_kernel<<<1024, 256, 0, stream>>>(Q, K, V, W_frag, b_all, weff, lh_b, out);
}